// Round 10
// baseline (21.907 us; speedup 1.0000x reference)
//
#include <hip/hip_runtime.h>
#include <hip/hip_bf16.h>

// LearnableInterpolation: out[b,t,n] = sum_o softmax_o(-3*(tpos[o,n]-tgt[t])^2) * x[b,o,n]
// B=32, L_org=L_to=2048, N=21. Softmax over o is a near-delta -> 17-tap window.
//
// R10: request-rate analysis: all fused-gather variants (R4/R6/R8/R9) sit at
// 4.13M divergent lane-requests / 256 CU / 16.3us = 1.03 req/cy/CU — the TA
// address-processing ceiling. Occupancy doubling gave +3% (R9) => pure
// request-throughput bound. Fix = coalesce BOTH sides:
//   k1: tiled transpose x -> xt[N,B,L] (proven in R2/R5), ~172K line-reqs.
//   k2: block=(32-t-tile, b), 2048 blocks (8/CU): stage all 21 channel
//       windows (len<=61) from xt with consecutive-tid loads; R9's exact
//       weight math per (tl,n); outputs through LDS -> 672 consecutive
//       scalar stores (HW-merged). ~0.5M line-requests total (8x fewer).

constexpr int LORG  = 2048;
constexpr int LTO   = 2048;
constexpr int NCH   = 21;
constexpr int BATCH = 32;
constexpr int W     = 8;
constexpr int NW    = 2 * W + 1;   // 17 taps
constexpr int TT    = 32;          // t-tile for k2 (window len <= 61 < 64)

constexpr float MIN_RATIO = 0.7f, MAX_RATIO = 1.3f;
constexpr float MIN_BIAS  = -4.0f, MAX_BIAS = 4.0f;
constexpr float NEG3LOG2E = -3.0f * 1.4426950408889634f;  // log2-domain scale

__device__ __forceinline__ int compute_o0(float tg, float bb, float ir) {
    const float ocf = (float)LORG + (tg - bb) * ir;
    int o0 = (int)floorf(ocf + 0.5f) - W;
    return max(0, min(LORG - NW, o0));
}

// ---------------- kernel 1: transpose x[B,LORG,NCH] -> xt[NCH,BATCH,LORG] ---
__global__ __launch_bounds__(256) void li_transpose(
    const float* __restrict__ x, float* __restrict__ xt)
{
    const int b  = blockIdx.y;
    const int o0 = blockIdx.x * 64;
    __shared__ float tile[64 * NCH];
    const float* src = x + ((size_t)b * LORG + o0) * NCH;
    for (int i = threadIdx.x; i < 64 * NCH; i += 256) tile[i] = src[i];
    __syncthreads();
    for (int j = threadIdx.x; j < 64 * NCH; j += 256) {
        const int n = j >> 6, k = j & 63;              // lane==k -> coalesced write
        xt[((size_t)(n * BATCH + b)) * LORG + o0 + k] = tile[k * NCH + n];
    }
}

// ---------------- kernel 2: all-coalesced interpolation ---------------------
__global__ __launch_bounds__(256) void li_interp(
    const float* __restrict__ xt,     // [NCH, BATCH, LORG]
    const float* __restrict__ rmo,
    const float* __restrict__ bias,
    float* __restrict__ out)          // [B, LTO, NCH]
{
    // swizzle: 2048 blocks = 8 XCD chunks of 256; within a chunk: 4 batches
    // x all 64 t-tiles -> each XCD's L2 holds 4 b-columns of xt (~700KB).
    const int h  = blockIdx.x;
    const int wk = (h & 7) * 256 + (h >> 3);
    const int b  = wk >> 6;                 // 0..31
    const int tt = wk & 63;                 // 0..63
    const int t0 = tt * TT;

    const int tid = threadIdx.x;

    __shared__ float xs[NCH][64];           // staged windows (5.25 KB)
    __shared__ float osh[TT * NCH];         // out tile, 672 floats (2.6 KB)
    __shared__ float rshv[NCH], bshv[NCH], irshv[NCH];
    __shared__ int   lov[NCH], lenv[NCH];

    // phase 0: per-channel params + window bounds
    if (tid < NCH) {
        const float r  = fminf(fmaxf(rmo[tid] + 1.0f, MIN_RATIO), MAX_RATIO);
        const float bb = fminf(fmaxf(bias[tid], MIN_BIAS), MAX_BIAS);
        const float ir = 1.0f / r;
        const int lo = compute_o0((float)(t0 - LTO), bb, ir);
        const int hi = compute_o0((float)(t0 + TT - 1 - LTO), bb, ir);
        rshv[tid]  = r;  bshv[tid] = bb;  irshv[tid] = ir;
        lov[tid]   = lo;
        lenv[tid]  = hi + NW - lo;          // <= ceil(31/0.7)+17 = 61
    }
    __syncthreads();

    // phase 1: stage 21 windows, consecutive-tid coalesced (64 floats/channel)
    for (int idx = tid; idx < NCH * 64; idx += 256) {
        const int n = idx >> 6, i = idx & 63;
        const int ic = min(i, lenv[n] - 1);             // clamp tail
        xs[n][i] = xt[((size_t)n * BATCH + b) * LORG + lov[n] + ic];
    }
    __syncthreads();

    // phase 2: compute; thread (tl = tid&31, cg = tid>>5) does ch {cg, cg+8, cg+16}
    const int tl = tid & 31;
    const int cg = tid >> 5;
    const float tg = (float)(t0 + tl - LTO);
    #pragma unroll
    for (int c = 0; c < 3; ++c) {
        const int n = cg + 8 * c;
        if (n < NCH) {
            const float r  = rshv[n];
            const float bb = bshv[n];
            const float ir = irshv[n];
            const int   o0 = compute_o0(tg, bb, ir);
            const int base = o0 - lov[n];
            float d = (float)(o0 - LORG) * r + bb - tg;   // d_j = d + j*r
            // analytic max of -3*d_j^2 over j in [0,16]
            float js = floorf(-d * ir + 0.5f);
            js = fminf(fmaxf(js, 0.0f), 16.0f);
            const float dstar = d + js * r;
            const float m = NEG3LOG2E * dstar * dstar;
            float s = 0.0f, acc = 0.0f;
            #pragma unroll
            for (int j = 0; j < NW; ++j) {
                const float wgt = exp2f(NEG3LOG2E * d * d - m);
                s += wgt;
                acc = fmaf(wgt, xs[n][base + j], acc);
                d += r;
            }
            osh[tl * NCH + n] = acc * (1.0f / s);
        }
    }
    __syncthreads();

    // phase 3: 672 consecutive scalar stores (HW-coalesced into ~42 lines)
    float* dst = out + ((size_t)b * LTO + t0) * NCH;
    for (int i = tid; i < TT * NCH; i += 256) dst[i] = osh[i];
}

// ---------------- fallback (R9 fused kernel) if ws too small ----------------
__global__ __launch_bounds__(256) void li_fused(
    const float* __restrict__ x,
    const float* __restrict__ rmo,
    const float* __restrict__ bias,
    float* __restrict__ out)
{
    const int NB = NCH * (LTO / 64) * (BATCH / 8);       // 2688
    const int h  = blockIdx.x;
    const int wk = (h & 7) * (NB / 8) + (h >> 3);
    const int bh = wk & 3;
    const int tn = wk >> 2;
    const int tt = tn / NCH;
    const int n  = tn - tt * NCH;
    const int t0 = tt * 64;
    const int tid = threadIdx.x;
    const int tl  = tid & 63;
    const int wv  = tid >> 6;
    const int b0  = bh * 8;

    __shared__ float xs[4][2][128];

    const float r  = fminf(fmaxf(rmo[n] + 1.0f, MIN_RATIO), MAX_RATIO);
    const float bb = fminf(fmaxf(bias[n], MIN_BIAS), MAX_BIAS);
    const float ir = 1.0f / r;
    const int lo  = compute_o0((float)(t0 - LTO), bb, ir);
    const int hi  = compute_o0((float)(t0 + 63 - LTO), bb, ir);
    const int len = hi + NW - lo;
    const int i0 = min(tl,      len - 1);
    const int i1 = min(tl + 64, len - 1);

    const int bA = b0 + wv;
    const float* colA = x + ((size_t)((bA    ) * LORG + lo)) * NCH + n;
    const float* colB = x + ((size_t)((bA + 4) * LORG + lo)) * NCH + n;
    const float a0 = colA[(size_t)i0 * NCH], a1 = colA[(size_t)i1 * NCH];
    const float c0 = colB[(size_t)i0 * NCH], c1 = colB[(size_t)i1 * NCH];

    const float tg = (float)(t0 + tl - LTO);
    const int   o0 = compute_o0(tg, bb, ir);
    const int base = o0 - lo;
    float d = (float)(o0 - LORG) * r + bb - tg;
    float js = floorf(-d * ir + 0.5f);
    js = fminf(fmaxf(js, 0.0f), 16.0f);
    const float dstar = d + js * r;
    const float m = NEG3LOG2E * dstar * dstar;
    float w[NW];
    float s = 0.0f;
    #pragma unroll
    for (int j = 0; j < NW; ++j) {
        w[j] = exp2f(NEG3LOG2E * d * d - m);
        s += w[j];
        d += r;
    }
    const float inv = 1.0f / s;

    xs[wv][0][tl] = a0; xs[wv][0][tl + 64] = a1;
    xs[wv][1][tl] = c0; xs[wv][1][tl + 64] = c1;

    float accA = 0.0f, accB = 0.0f;
    #pragma unroll
    for (int j = 0; j < NW; ++j) {
        accA = fmaf(w[j], xs[wv][0][base + j], accA);
        accB = fmaf(w[j], xs[wv][1][base + j], accB);
    }
    out[((size_t)(bA    ) * LTO + t0 + tl) * NCH + n] = accA * inv;
    out[((size_t)(bA + 4) * LTO + t0 + tl) * NCH + n] = accB * inv;
}

extern "C" void kernel_launch(void* const* d_in, const int* in_sizes, int n_in,
                              void* d_out, int out_size, void* d_ws, size_t ws_size,
                              hipStream_t stream) {
    const float* x    = (const float*)d_in[0];
    const float* rmo  = (const float*)d_in[1];
    const float* bias = (const float*)d_in[2];
    float* out = (float*)d_out;

    const size_t xt_bytes = (size_t)NCH * BATCH * LORG * sizeof(float);
    if (ws_size >= xt_bytes) {
        float* xt = (float*)d_ws;
        li_transpose<<<dim3(LORG / 64, BATCH), 256, 0, stream>>>(x, xt);
        li_interp<<<2048, 256, 0, stream>>>(xt, rmo, bias, out);
    } else {
        li_fused<<<2688, 256, 0, stream>>>(x, rmo, bias, out);
    }
}

// Round 11
// 17.648 us; speedup vs baseline: 1.2413x; 1.2413x over previous
//
#include <hip/hip_runtime.h>
#include <hip/hip_bf16.h>

// LearnableInterpolation: out[b,t,n] = sum_o softmax_o(-3*(tpos[o,n]-tgt[t])^2) * x[b,o,n]
// B=32, L_org=L_to=2048, N=21. Softmax over o is a near-delta -> 17-tap window.
//
// R11: single kernel (two-kernel = +5us dispatch/coherence tax, proven 3x).
// Block = (b, 64-t-tile) covering ALL 21 channels, 1024 blocks:
//  - per-channel windows (len<=107) gathered to LDS; channels SORTED by lo so
//    overlapping windows stage concurrently -> L1/MSHR dedups the shared
//    lines (x rows are 84B ~ 2 lines shared by all 21 channels);
//  - wave-local stage->compute: each wave stages exactly the channels it
//    computes, so NO barrier between stage and compute (wave-internal
//    vmcnt/lgkmcnt ordering suffices);
//  - outputs staged in LDS, written as 1344 CONSECUTIVE floats per block
//    (store line-requests 1.38M -> ~0.09M; R7 taught us scattered stores
//    must stay in L2 write-back, so plain dwords).

constexpr int LORG  = 2048;
constexpr int LTO   = 2048;
constexpr int NCH   = 21;
constexpr int BATCH = 32;
constexpr int W     = 8;
constexpr int NW    = 2 * W + 1;   // 17 taps
constexpr int TT    = 64;          // t-tile
constexpr int NBLK  = BATCH * (LTO / TT);   // 32*32 = 1024

constexpr float MIN_RATIO = 0.7f, MAX_RATIO = 1.3f;
constexpr float MIN_BIAS  = -4.0f, MAX_BIAS = 4.0f;
constexpr float NEG3LOG2E = -3.0f * 1.4426950408889634f;  // log2-domain scale

__device__ __forceinline__ int compute_o0(float tg, float bb, float ir) {
    const float ocf = (float)LORG + (tg - bb) * ir;
    int o0 = (int)floorf(ocf + 0.5f) - W;
    return max(0, min(LORG - NW, o0));
}

__global__ __launch_bounds__(256) void li_fused(
    const float* __restrict__ x,      // [B, LORG, NCH]
    const float* __restrict__ rmo,    // [NCH]
    const float* __restrict__ bias,   // [NCH]
    float* __restrict__ out)          // [B, LTO, NCH]
{
    // XCD swizzle: 1024 = 8*128; each XCD gets 4 full b-slabs (b = wk>>5),
    // so its L2 working set is 4 x 172KB of x + outputs.
    const int h  = blockIdx.x;
    const int wk = (h & 7) * (NBLK / 8) + (h >> 3);
    const int b  = wk >> 5;                // 0..31
    const int tt = wk & 31;                // 0..31
    const int t0 = tt * TT;

    const int tid = threadIdx.x;
    const int tl  = tid & 63;              // this thread's t within the tile
    const int wv  = tid >> 6;              // wave id 0..3

    __shared__ float xs[NCH][128];         // per-channel windows (10.5 KB)
    __shared__ float osh[TT * NCH];        // out tile, 1344 floats (5.25 KB)
    __shared__ float rsh[NCH], bsh[NCH], irsh[NCH];
    __shared__ int   lov[NCH], lenv[NCH], order[NCH];

    // ---- phase 0: per-channel params + window bounds (first 21 lanes) ----
    if (tid < NCH) {
        const float r  = fminf(fmaxf(rmo[tid] + 1.0f, MIN_RATIO), MAX_RATIO);
        const float bb = fminf(fmaxf(bias[tid], MIN_BIAS), MAX_BIAS);
        const float ir = 1.0f / r;
        const int lo = compute_o0((float)(t0 - LTO), bb, ir);
        const int hi = compute_o0((float)(t0 + TT - 1 - LTO), bb, ir);
        rsh[tid]  = r;  bsh[tid] = bb;  irsh[tid] = ir;
        lov[tid]  = lo;
        lenv[tid] = hi + NW - lo;          // <= ceil(63/0.7)+17 = 107 < 128
    }
    __syncthreads();
    // rank channels by lo (overlapping windows -> adjacent slots -> staged
    // concurrently across waves -> L1/MSHR line dedup)
    if (tid < NCH) {
        const int lo = lov[tid];
        int rank = 0;
        for (int mth = 0; mth < NCH; ++mth) {
            const int lm = lov[mth];
            rank += (lm < lo) || (lm == lo && mth < tid);
        }
        order[rank] = tid;
    }
    __syncthreads();

    // ---- phase 1: wave-local stage (slots wv, wv+4, ...) ----
    for (int s = wv; s < NCH; s += 4) {
        const int n   = order[s];
        const int lo  = lov[n];
        const int len = lenv[n];
        const float* col = x + ((size_t)(b * LORG + lo)) * NCH + n;
        const int i0 = min(tl,      len - 1);   // clamp tail (dup loads, same line)
        const int i1 = min(tl + 64, len - 1);
        xs[n][tl]      = col[(size_t)i0 * NCH];
        xs[n][tl + 64] = col[(size_t)i1 * NCH];
    }

    // ---- phase 2: wave-local compute (same slots; no barrier needed) ----
    const float tg = (float)(t0 + tl - LTO);
    for (int s = wv; s < NCH; s += 4) {
        const int n  = order[s];
        const float r  = rsh[n];
        const float bb = bsh[n];
        const float ir = irsh[n];
        const int   o0 = compute_o0(tg, bb, ir);
        const int base = o0 - lov[n];
        float d = (float)(o0 - LORG) * r + bb - tg;   // d_j = d + j*r
        // analytic max of -3*d_j^2 over j in [0,16]: nearest j to -d/r
        float js = floorf(-d * ir + 0.5f);
        js = fminf(fmaxf(js, 0.0f), 16.0f);
        const float dstar = d + js * r;
        const float m = NEG3LOG2E * dstar * dstar;    // log2-domain max
        float sum = 0.0f, acc = 0.0f;
        #pragma unroll
        for (int j = 0; j < NW; ++j) {
            const float wgt = exp2f(NEG3LOG2E * d * d - m);
            sum += wgt;
            acc = fmaf(wgt, xs[n][base + j], acc);
            d += r;
        }
        osh[tl * NCH + n] = acc * (1.0f / sum);       // stride 21: conflict-free
    }
    __syncthreads();

    // ---- phase 3: coalesced store, 1344 consecutive floats ----
    float* dst = out + ((size_t)b * LTO + t0) * NCH;
    for (int i = tid; i < TT * NCH; i += 256) dst[i] = osh[i];
}

extern "C" void kernel_launch(void* const* d_in, const int* in_sizes, int n_in,
                              void* d_out, int out_size, void* d_ws, size_t ws_size,
                              hipStream_t stream) {
    const float* x    = (const float*)d_in[0];
    const float* rmo  = (const float*)d_in[1];
    const float* bias = (const float*)d_in[2];
    float* out = (float*)d_out;

    li_fused<<<NBLK, 256, 0, stream>>>(x, rmo, bias, out);
}